// Round 16
// baseline (38.491 us; speedup 1.0000x reference)
//
#include <hip/hip_runtime.h>
#include <math.h>

#define H 256
#define EPS 1e-4f

// ---- DPP helpers (gfx9/CDNA), bound_ctrl:0 (0-fill invalid lanes) ----
template <int CTRL>
__device__ __forceinline__ float dpp0(float x) {
    return __int_as_float(
        __builtin_amdgcn_update_dpp(0, __float_as_int(x), CTRL, 0xf, 0xf, true));
}
__device__ __forceinline__ float rdlane(float x, int l) {
    return __int_as_float(__builtin_amdgcn_readlane(__float_as_int(x), l));
}
__device__ __forceinline__ float frcp_fast(float v) { return __builtin_amdgcn_rcpf(v); }
__device__ __forceinline__ float frcp_nr(float v) {
    float r = __builtin_amdgcn_rcpf(v);
    return fmaf(r, fmaf(-v, r, 1.0f), r);
}
__device__ __forceinline__ void wave_red_sum2(float& a, float& b) {
    a += dpp0<0x111>(a);  b += dpp0<0x111>(b);
    a += dpp0<0x112>(a);  b += dpp0<0x112>(b);
    a += dpp0<0x114>(a);  b += dpp0<0x114>(b);
    a += dpp0<0x118>(a);  b += dpp0<0x118>(b);
    a += dpp0<0x142>(a);  b += dpp0<0x142>(b);
    a += dpp0<0x143>(a);  b += dpp0<0x143>(b);
    a = rdlane(a, 63);
    b = rdlane(b, 63);
}

// Producer-side Schur step (F,B,R + scalar lookahead chain). Outputs (g,mu)
// into registers; LDS publishing is batched OUTSIDE (2 x b128 per 4 steps).
#define PSTEP(KF1, KF2, LN1, LN2, GOUT, MUOUT) do {                     \
    float g  = -sF * isB;                                               \
    float sE = fmaf(g, sF, sB);              /* B_{k+1}[k+1] */         \
    isB = frcp_fast(sE);                                                \
    float mu = sR * isB;                                                \
    GOUT = g; MUOUT = mu;                                               \
    float rlF2 = rdlane(F[KF2], (LN2));      /* F_k[k+2] */             \
    float rlB1 = rdlane(B[KF1], (LN1));      /* B_k[k+1] */             \
    float rlR2 = rdlane(R[KF2], (LN2));      /* R_k[k+2] */             \
    sF = fmaf(g, rlB1, rlF2);                                           \
    float tB2 = fmaf(g, rlF2, rlB1);                                    \
    sR = fmaf(-mu, tB2, rlR2);                                          \
    sB = sE;                                                            \
    float sb0 = dpp0<0x138>(B[3]);           /* wave_shr:1 */           \
    float nB0 = fmaf(g, F[0], sb0);                                     \
    float nB1 = fmaf(g, F[1], B[0]);                                    \
    float nB2 = fmaf(g, F[2], B[1]);                                    \
    float nB3 = fmaf(g, F[3], B[2]);                                    \
    float nF0 = fmaf(g, sb0,  F[0]);                                    \
    float nF1 = fmaf(g, B[0], F[1]);                                    \
    float nF2 = fmaf(g, B[1], F[2]);                                    \
    float nF3 = fmaf(g, B[2], F[3]);                                    \
    R[0] = fmaf(-mu, nB0, R[0]);                                        \
    R[1] = fmaf(-mu, nB1, R[1]);                                        \
    R[2] = fmaf(-mu, nB2, R[2]);                                        \
    R[3] = fmaf(-mu, nB3, R[3]);                                        \
    B[0]=nB0; B[1]=nB1; B[2]=nB2; B[3]=nB3;                             \
    F[0]=nF0; F[1]=nF1; F[2]=nF2; F[3]=nF3;                             \
} while (0)

// Consumer-side step: x,a,ra from a published (g,mu) pair.
#define CSTEP(G, MU) do {                                               \
    float g = (G), mu = (MU);                                           \
    float sr0 = dpp0<0x138>(ra[3]);                                     \
    float nr0 = fmaf(g, a[0], sr0);                                     \
    float nr1 = fmaf(g, a[1], ra[0]);                                   \
    float nr2 = fmaf(g, a[2], ra[1]);                                   \
    float nr3 = fmaf(g, a[3], ra[2]);                                   \
    float na0 = fmaf(g, sr0,  a[0]);                                    \
    float na1 = fmaf(g, ra[0], a[1]);                                   \
    float na2 = fmaf(g, ra[1], a[2]);                                   \
    float na3 = fmaf(g, ra[2], a[3]);                                   \
    x[0] = fmaf(mu, nr0, x[0]);                                         \
    x[1] = fmaf(mu, nr1, x[1]);                                         \
    x[2] = fmaf(mu, nr2, x[2]);                                         \
    x[3] = fmaf(mu, nr3, x[3]);                                         \
    a[0]=na0; a[1]=na1; a[2]=na2; a[3]=na3;                             \
    ra[0]=nr0; ra[1]=nr1; ra[2]=nr2; ra[3]=nr3;                         \
} while (0)

// 2 waves per batch: wave0 = producer (F,B,R + scalars -> (g,mu) stream),
// wave1 = consumer (x,a,ra + loss). Lean handshake: register-batched b128
// gmu stores (per 4 steps), RELEASE flag per 16 steps, consumer prefetches
// 16 pairs/group. Producer never waits on consumer -> no deadlock.
__global__ __launch_bounds__(128) void awloss_batch(
        const float* __restrict__ recon,
        const float* __restrict__ target,
        float* __restrict__ losses) {
    const int b    = blockIdx.x;
    const int tid  = threadIdx.x;
    const int lane = tid & 63;
    const int wid  = tid >> 6;
    const bool l0  = (lane == 0);

    __shared__ __align__(16) float tgtp[576];   // target, zero-padded
    __shared__ __align__(16) float recp[576];   // recon at [127..382], zeros else
    __shared__ __align__(16) float accR[256];   // autocorr  (published by wave0)
    __shared__ __align__(16) float accBs[256];  // cross-corr (published by wave1)
    __shared__ __align__(16) float2 gmu[256];   // (g, mu) stream
    __shared__ int done;

    if (tid == 0) done = -1;
    #pragma unroll
    for (int c = 0; c < 5; ++c) {
        int i = c * 128 + tid;
        if (i < 576) { tgtp[i] = 0.f; recp[i] = 0.f; }
    }
    __syncthreads();
    if (wid == 0) {
        float4 tv4 = ((const float4*)(target + b * H))[lane];
        *(float4*)&tgtp[4 * lane] = tv4;
    } else {
        float4 rv4 = ((const float4*)(recon + b * H))[lane];
        recp[127 + 4*lane + 0] = rv4.x;
        recp[127 + 4*lane + 1] = rv4.y;
        recp[127 + 4*lane + 2] = rv4.z;
        recp[127 + 4*lane + 3] = rv4.w;
    }
    __syncthreads();

    // --- correlation, split: wave0 -> racc (window tgtp), wave1 -> bacc
    //     (window recp); t[m] quad via uniform broadcast b128 read ---
    const float* W = (wid == 0) ? tgtp : recp;
    float acc[4] = {0.f, 0.f, 0.f, 0.f};
    float4 W0 = *(const float4*)&W[4 * lane];
    for (int m0 = 0; m0 < 256; m0 += 4) {
        float4 N  = *(const float4*)&W[m0 + 4 + 4 * lane];
        float4 tq = *(const float4*)&tgtp[m0];           // uniform broadcast
        acc[0]=fmaf(tq.x,W0.x,acc[0]); acc[1]=fmaf(tq.x,W0.y,acc[1]);
        acc[2]=fmaf(tq.x,W0.z,acc[2]); acc[3]=fmaf(tq.x,W0.w,acc[3]);
        acc[0]=fmaf(tq.y,W0.y,acc[0]); acc[1]=fmaf(tq.y,W0.z,acc[1]);
        acc[2]=fmaf(tq.y,W0.w,acc[2]); acc[3]=fmaf(tq.y,N.x ,acc[3]);
        acc[0]=fmaf(tq.z,W0.z,acc[0]); acc[1]=fmaf(tq.z,W0.w,acc[1]);
        acc[2]=fmaf(tq.z,N.x ,acc[2]); acc[3]=fmaf(tq.z,N.y ,acc[3]);
        acc[0]=fmaf(tq.w,W0.w,acc[0]); acc[1]=fmaf(tq.w,N.x ,acc[1]);
        acc[2]=fmaf(tq.w,N.y ,acc[2]); acc[3]=fmaf(tq.w,N.z ,acc[3]);
        W0 = N;
    }
    if (wid == 0) *(float4*)&accR [4*lane] = make_float4(acc[0],acc[1],acc[2],acc[3]);
    else          *(float4*)&accBs[4*lane] = make_float4(acc[0],acc[1],acc[2],acc[3]);
    __syncthreads();
    // ---- no barriers below this line; waves fully diverge ----

    if (wid == 0) {
        // ================= producer =================
        float t0v = rdlane(acc[0], 0) + EPS;      // acc == racc
        float it0 = frcp_nr(t0v);
        float F[4], B[4], R[4];
        #pragma unroll
        for (int c = 0; c < 4; ++c) {
            float rh = acc[c] * it0;
            if (c == 0) rh = l0 ? 1.0f : rh;
            F[c] = rh; B[c] = rh;
        }
        float4 bb4 = *(const float4*)&accBs[4 * lane];
        float bb0 = rdlane(bb4.x, 0) * it0;
        R[0] = fmaf(-bb0, F[0], bb4.x * it0);
        R[1] = fmaf(-bb0, F[1], bb4.y * it0);
        R[2] = fmaf(-bb0, F[2], bb4.z * it0);
        R[3] = fmaf(-bb0, F[3], bb4.w * it0);

        float sF  = rdlane(F[1], 0);
        float sB  = 1.0f, isB = 1.0f;
        float sR  = rdlane(R[1], 0);

        for (int t = 0; t < 63; ++t) {
            int k = 4 * t;
            float g0,m0v,g1,m1v,g2,m2v,g3,m3v;
            PSTEP(1, 2, t,     t,     g0, m0v);
            PSTEP(2, 3, t,     t,     g1, m1v);
            PSTEP(3, 0, t,     t + 1, g2, m2v);
            PSTEP(0, 1, t + 1, t + 1, g3, m3v);
            if (l0) {
                *(float4*)&gmu[k]     = make_float4(g0, m0v, g1, m1v);
                *(float4*)&gmu[k + 2] = make_float4(g2, m2v, g3, m3v);
            }
            if ((t & 3) == 3)
                if (l0) __hip_atomic_store(&done, k + 3, __ATOMIC_RELEASE,
                                           __HIP_MEMORY_SCOPE_WORKGROUP);
        }
        {   // k = 252, 253, then 254 (scalars only)
            float g0,m0v,g1,m1v;
            PSTEP(1, 2, 63, 63, g0, m0v);
            PSTEP(2, 3, 63, 63, g1, m1v);
            float g  = -sF * isB;
            float sE = fmaf(g, sF, sB);
            float mu = sR * frcp_fast(sE);
            if (l0) {
                *(float4*)&gmu[252] = make_float4(g0, m0v, g1, m1v);
                gmu[254] = make_float2(g, mu);
                __hip_atomic_store(&done, 255, __ATOMIC_RELEASE,
                                   __HIP_MEMORY_SCOPE_WORKGROUP);
            }
        }
    } else {
        // ================= consumer =================
        float t0v = accR[0] + EPS;                // uniform LDS read
        float it0 = frcp_nr(t0v);
        float bb0 = rdlane(acc[0], 0) * it0;      // acc == bacc
        float x[4]  = {0.f,0.f,0.f,0.f};
        float a[4]  = {0.f,0.f,0.f,0.f};
        float ra[4] = {0.f,0.f,0.f,0.f};
        if (l0) { x[0] = bb0; a[0] = 1.0f; ra[0] = 1.0f; }

        for (int T = 0; T < 15; ++T) {            // steps 16T .. 16T+15
            int tgt_step = 16 * T + 15;
            while (__hip_atomic_load(&done, __ATOMIC_ACQUIRE,
                                     __HIP_MEMORY_SCOPE_WORKGROUP) < tgt_step) {}
            float2 gm = gmu[16 * T + (lane & 15)];
            #pragma unroll
            for (int s = 0; s < 16; ++s)
                CSTEP(rdlane(gm.x, s), rdlane(gm.y, s));
        }
        while (__hip_atomic_load(&done, __ATOMIC_ACQUIRE,
                                 __HIP_MEMORY_SCOPE_WORKGROUP) < 255) {}
        float2 gm = gmu[240 + (lane & 15)];       // steps 240 .. 254 (15)
        #pragma unroll
        for (int s = 0; s < 15; ++s)
            CSTEP(rdlane(gm.x, s), rdlane(gm.y, s));

        // --- loss: 0.5*sqrt(sum((T*v)^2)/sum(v^2)), elements e = 4*lane+c ---
        float sT = 0.f, sV = 0.f;
        const float dxg = 20.0f / 255.0f;
        #pragma unroll
        for (int c = 0; c < 4; ++c) {
            float v  = x[c];
            float u  = -10.0f + dxg * (float)(4*lane + c) + 0.5f * dxg;
            float Ti = 1.0f - expf(-0.5f * u * u);   // T normalizers == 1.0f
            float tw = Ti * v;
            sT += tw * tw;
            sV += v * v;
        }
        wave_red_sum2(sT, sV);
        if (l0) losses[b] = 0.5f * sqrtf(sT / sV);
    }
}

// deterministic final reduction of 512 per-batch losses
__global__ __launch_bounds__(64) void awloss_reduce(
        const float* __restrict__ losses, float* __restrict__ out) {
    int lane = threadIdx.x;
    float s = 0.f;
    #pragma unroll
    for (int c = 0; c < 8; ++c) s += losses[c * 64 + lane];
    float d = 0.f;
    wave_red_sum2(s, d);
    if (lane == 0) out[0] = s;
}

extern "C" void kernel_launch(void* const* d_in, const int* in_sizes, int n_in,
                              void* d_out, int out_size, void* d_ws, size_t ws_size,
                              hipStream_t stream) {
    const float* recon  = (const float*)d_in[0];
    const float* target = (const float*)d_in[1];
    float* losses = (float*)d_ws;   // 512 floats
    float* out    = (float*)d_out;

    awloss_batch<<<512, 128, 0, stream>>>(recon, target, losses);
    awloss_reduce<<<1, 64, 0, stream>>>(losses, out);
}

// Round 17
// 28.574 us; speedup vs baseline: 1.3471x; 1.3471x over previous
//
#include <hip/hip_runtime.h>
#include <math.h>

#define H 256
#define EPS 1e-4f

// ---- DPP helpers (gfx9/CDNA), bound_ctrl:0 (0-fill invalid lanes) ----
template <int CTRL>
__device__ __forceinline__ float dpp0(float x) {
    return __int_as_float(
        __builtin_amdgcn_update_dpp(0, __float_as_int(x), CTRL, 0xf, 0xf, true));
}
__device__ __forceinline__ float rdlane(float x, int l) {
    return __int_as_float(__builtin_amdgcn_readlane(__float_as_int(x), l));
}
__device__ __forceinline__ float frcp_fast(float v) { return __builtin_amdgcn_rcpf(v); }
__device__ __forceinline__ float frcp_nr(float v) {
    float r = __builtin_amdgcn_rcpf(v);
    return fmaf(r, fmaf(-v, r, 1.0f), r);
}
// full-wave sum of two values, result uniform
__device__ __forceinline__ void wave_red_sum2(float& a, float& b) {
    a += dpp0<0x111>(a);  b += dpp0<0x111>(b);
    a += dpp0<0x112>(a);  b += dpp0<0x112>(b);
    a += dpp0<0x114>(a);  b += dpp0<0x114>(b);
    a += dpp0<0x118>(a);  b += dpp0<0x118>(b);
    a += dpp0<0x142>(a);  b += dpp0<0x142>(b);
    a += dpp0<0x143>(a);  b += dpp0<0x143>(b);
    a = rdlane(a, 63);
    b = rdlane(b, 63);
}

// Support-packed Schur step k -> k+1 (R12 champion, unchanged).
// P = a|F, Q = ra|B, X = x|-R;  P' = P + g*sh1(Q);  Q' = sh1(Q) + g*P;
// X' = X + mu*Q'.  Boundary: P'[k+1] <- g, X'[k+1] <- mu via cmp+cndmask.
#define STEP(KF1, KF2, LN1, LN2) do {                                   \
    float g  = -sF * isB;                                               \
    float sE = fmaf(g, sF, sB);              /* B_{k+1}[k+1] */         \
    isB = frcp_fast(sE);                                                \
    float mu = -sRt * isB;                                              \
    float rlF2 = rdlane(P[KF2], (LN2));      /* F_k[k+2]  */            \
    float rlB1 = rdlane(Q[KF1], (LN1));      /* B_k[k+1]  */            \
    float rlR2 = rdlane(X[KF2], (LN2));      /* -R_k[k+2] */            \
    sF  = fmaf(g, rlB1, rlF2);               /* F_{k+1}[k+2] */         \
    float tB2 = fmaf(g, rlF2, rlB1);         /* B_{k+1}[k+2] */         \
    sRt = fmaf(mu, tB2, rlR2);               /* -R_{k+1}[k+2] */        \
    sB  = sE;                                                           \
    float shq0 = dpp0<0x138>(Q[3]);          /* wave_shr:1 */           \
    float nQ0 = fmaf(g, P[0], shq0);                                    \
    float nQ1 = fmaf(g, P[1], Q[0]);                                    \
    float nQ2 = fmaf(g, P[2], Q[1]);                                    \
    float nQ3 = fmaf(g, P[3], Q[2]);                                    \
    float nP0 = fmaf(g, shq0, P[0]);                                    \
    float nP1 = fmaf(g, Q[0],  P[1]);                                   \
    float nP2 = fmaf(g, Q[1],  P[2]);                                   \
    float nP3 = fmaf(g, Q[2],  P[3]);                                   \
    X[0] = fmaf(mu, nQ0, X[0]);                                         \
    X[1] = fmaf(mu, nQ1, X[1]);                                         \
    X[2] = fmaf(mu, nQ2, X[2]);                                         \
    X[3] = fmaf(mu, nQ3, X[3]);                                         \
    bool bm = (lane == (LN1));               /* element k+1's lane */   \
    P[0]=nP0; P[1]=nP1; P[2]=nP2; P[3]=nP3;                             \
    Q[0]=nQ0; Q[1]=nQ1; Q[2]=nQ2; Q[3]=nQ3;                             \
    P[KF1] = bm ? g  : P[KF1];                                          \
    X[KF1] = bm ? mu : X[KF1];                                          \
} while (0)

// One block of 16 fmas for m = M..M+3 using windows U (@M-aligned) and
// V (@M+4): accumulation order per racc[c]/bacc[c] identical to R12.
#define CORR4(tq, Ut, Ur, Vt, Vr) do {                                  \
    racc[0] = fmaf(tq.x, Ut.x, racc[0]); bacc[0] = fmaf(tq.x, Ur.x, bacc[0]); \
    racc[1] = fmaf(tq.x, Ut.y, racc[1]); bacc[1] = fmaf(tq.x, Ur.y, bacc[1]); \
    racc[2] = fmaf(tq.x, Ut.z, racc[2]); bacc[2] = fmaf(tq.x, Ur.z, bacc[2]); \
    racc[3] = fmaf(tq.x, Ut.w, racc[3]); bacc[3] = fmaf(tq.x, Ur.w, bacc[3]); \
    racc[0] = fmaf(tq.y, Ut.y, racc[0]); bacc[0] = fmaf(tq.y, Ur.y, bacc[0]); \
    racc[1] = fmaf(tq.y, Ut.z, racc[1]); bacc[1] = fmaf(tq.y, Ur.z, bacc[1]); \
    racc[2] = fmaf(tq.y, Ut.w, racc[2]); bacc[2] = fmaf(tq.y, Ur.w, bacc[2]); \
    racc[3] = fmaf(tq.y, Vt.x, racc[3]); bacc[3] = fmaf(tq.y, Vr.x, bacc[3]); \
    racc[0] = fmaf(tq.z, Ut.z, racc[0]); bacc[0] = fmaf(tq.z, Ur.z, bacc[0]); \
    racc[1] = fmaf(tq.z, Ut.w, racc[1]); bacc[1] = fmaf(tq.z, Ur.w, bacc[1]); \
    racc[2] = fmaf(tq.z, Vt.x, racc[2]); bacc[2] = fmaf(tq.z, Vr.x, bacc[2]); \
    racc[3] = fmaf(tq.z, Vt.y, racc[3]); bacc[3] = fmaf(tq.z, Vr.y, bacc[3]); \
    racc[0] = fmaf(tq.w, Ut.w, racc[0]); bacc[0] = fmaf(tq.w, Ur.w, bacc[0]); \
    racc[1] = fmaf(tq.w, Vt.x, racc[1]); bacc[1] = fmaf(tq.w, Vr.x, bacc[1]); \
    racc[2] = fmaf(tq.w, Vt.y, racc[2]); bacc[2] = fmaf(tq.w, Vr.y, bacc[2]); \
    racc[3] = fmaf(tq.w, Vt.z, racc[3]); bacc[3] = fmaf(tq.w, Vr.z, bacc[3]); \
} while (0)

// One wave per batch. Schur solve of symmetric Toeplitz A v = b.
__global__ __launch_bounds__(64) void awloss_batch(
        const float* __restrict__ recon,
        const float* __restrict__ target,
        float* __restrict__ losses) {
    const int b    = blockIdx.x;
    const int lane = threadIdx.x;
    const bool l0  = (lane == 0);

    __shared__ __align__(16) float tgtp[576];   // t padded with zeros
    __shared__ __align__(16) float recp[576];   // rec at [127..382], zeros else

    const float4 tv4 = ((const float4*)(target + b * H))[lane];
    const float4 rv4 = ((const float4*)(recon  + b * H))[lane];

    #pragma unroll
    for (int c = 0; c < 9; ++c) { tgtp[c*64+lane] = 0.f; recp[c*64+lane] = 0.f; }
    __syncthreads();
    *(float4*)&tgtp[4*lane] = tv4;
    recp[127 + 4*lane + 0] = rv4.x;
    recp[127 + 4*lane + 1] = rv4.y;
    recp[127 + 4*lane + 2] = rv4.z;
    recp[127 + 4*lane + 3] = rv4.w;
    __syncthreads();

    // --- correlation r[d], b[d], lane-major d = 4*lane+c.
    //     Ping-pong sliding window (x2 unroll): no register copies.
    //     fma sequence per accumulator identical to R12 -> bitwise-same. ---
    float racc[4] = {0.f,0.f,0.f,0.f}, bacc[4] = {0.f,0.f,0.f,0.f};
    const int e0 = 4 * lane;
    float4 At = *(const float4*)&tgtp[e0];
    float4 Ar = *(const float4*)&recp[e0];
    for (int m0 = 0; m0 < 256; m0 += 8) {
        float4 Bt = *(const float4*)&tgtp[m0 + 4 + e0];
        float4 Br = *(const float4*)&recp[m0 + 4 + e0];
        float4 tqa = *(const float4*)&tgtp[m0];          // uniform broadcast
        CORR4(tqa, At, Ar, Bt, Br);                      // m = m0 .. m0+3
        At = *(const float4*)&tgtp[m0 + 8 + e0];
        Ar = *(const float4*)&recp[m0 + 8 + e0];
        float4 tqb = *(const float4*)&tgtp[m0 + 4];
        CORR4(tqb, Bt, Br, At, Ar);                      // m = m0+4 .. m0+7
    }

    // --- normalize; init packed state (lane-major e = 4*lane+c) ---
    float t0v = rdlane(racc[0], 0) + EPS;
    float it0 = frcp_nr(t0v);
    float P[4], Q[4], X[4];
    #pragma unroll
    for (int c = 0; c < 4; ++c) {
        float rh = racc[c] * it0;
        if (c == 0) rh = l0 ? 1.0f : rh;   // rho[0]=1; a_0[0]=1, B_0[0]=1
        P[c] = rh; Q[c] = rh;              // P = a|F = rho; Q = ra|B = rho
    }
    float bb0 = rdlane(bacc[0], 0) * it0;
    #pragma unroll
    for (int c = 0; c < 4; ++c) {
        float bvv = bacc[c] * it0;
        X[c] = fmaf(bb0, P[c], -bvv);      // -R_0 = bb0*rho - bb
    }
    if (l0) X[0] = bb0;                    // x_0[0] = bb0

    float sF  = rdlane(P[1], 0);           // F_0[1] = rho[1]
    float sB  = 1.0f, isB = 1.0f;
    float sRt = rdlane(X[1], 0);           // -R_0[1]

    // --- 255 Schur steps, x4 unrolled for literal register indices ---
    for (int t = 0; t < 63; ++t) {
        STEP(1, 2, t, t);                  // k = 4t
        STEP(2, 3, t, t);                  // k = 4t+1
        STEP(3, 0, t, t + 1);              // k = 4t+2
        STEP(0, 1, t + 1, t + 1);          // k = 4t+3
    }
    STEP(1, 2, 63, 63);                    // k = 252
    STEP(2, 3, 63, 63);                    // k = 253
    {   // k = 254: only mu and the X update matter (element 255 <- mu)
        float g  = -sF * isB;
        float sE = fmaf(g, sF, sB);
        float mu = -sRt * frcp_fast(sE);
        float shq0 = dpp0<0x138>(Q[3]);
        float nQ0 = fmaf(g, P[0], shq0);
        float nQ1 = fmaf(g, P[1], Q[0]);
        float nQ2 = fmaf(g, P[2], Q[1]);
        float nQ3 = fmaf(g, P[3], Q[2]);
        X[0] = fmaf(mu, nQ0, X[0]);
        X[1] = fmaf(mu, nQ1, X[1]);
        X[2] = fmaf(mu, nQ2, X[2]);
        X[3] = fmaf(mu, nQ3, X[3]);
        X[3] = (lane == 63) ? mu : X[3];
    }

    // --- loss: 0.5*sqrt(sum((T*v)^2)/sum(v^2)), elements e = 4*lane+c ---
    float sT = 0.f, sV = 0.f;
    const float dxg = 20.0f / 255.0f;
    #pragma unroll
    for (int c = 0; c < 4; ++c) {
        float v  = X[c];
        float u  = -10.0f + dxg * (float)(e0 + c) + 0.5f * dxg;
        float Ti = 1.0f - expf(-0.5f * u * u);   // T normalizers == 1.0f in f32
        float tw = Ti * v;
        sT += tw * tw;
        sV += v * v;
    }
    wave_red_sum2(sT, sV);
    if (l0) losses[b] = 0.5f * sqrtf(sT / sV);
}

// deterministic final reduction of 512 per-batch losses
__global__ __launch_bounds__(64) void awloss_reduce(
        const float* __restrict__ losses, float* __restrict__ out) {
    int lane = threadIdx.x;
    float s = 0.f;
    #pragma unroll
    for (int c = 0; c < 8; ++c) s += losses[c * 64 + lane];
    float d = 0.f;
    wave_red_sum2(s, d);
    if (lane == 0) out[0] = s;
}

extern "C" void kernel_launch(void* const* d_in, const int* in_sizes, int n_in,
                              void* d_out, int out_size, void* d_ws, size_t ws_size,
                              hipStream_t stream) {
    const float* recon  = (const float*)d_in[0];
    const float* target = (const float*)d_in[1];
    float* losses = (float*)d_ws;   // 512 floats
    float* out    = (float*)d_out;

    awloss_batch<<<512, 64, 0, stream>>>(recon, target, losses);
    awloss_reduce<<<1, 64, 0, stream>>>(losses, out);
}

// Round 18
// 28.496 us; speedup vs baseline: 1.3508x; 1.0028x over previous
//
#include <hip/hip_runtime.h>
#include <math.h>

#define H 256
#define EPS 1e-4f

// ---- DPP helpers (gfx9/CDNA), bound_ctrl:0 (0-fill invalid lanes) ----
template <int CTRL>
__device__ __forceinline__ float dpp0(float x) {
    return __int_as_float(
        __builtin_amdgcn_update_dpp(0, __float_as_int(x), CTRL, 0xf, 0xf, true));
}
__device__ __forceinline__ float rdlane(float x, int l) {
    return __int_as_float(__builtin_amdgcn_readlane(__float_as_int(x), l));
}
__device__ __forceinline__ float frcp_fast(float v) { return __builtin_amdgcn_rcpf(v); }
__device__ __forceinline__ float frcp_nr(float v) {
    float r = __builtin_amdgcn_rcpf(v);
    return fmaf(r, fmaf(-v, r, 1.0f), r);
}
// full-wave sum of two values, result uniform
__device__ __forceinline__ void wave_red_sum2(float& a, float& b) {
    a += dpp0<0x111>(a);  b += dpp0<0x111>(b);
    a += dpp0<0x112>(a);  b += dpp0<0x112>(b);
    a += dpp0<0x114>(a);  b += dpp0<0x114>(b);
    a += dpp0<0x118>(a);  b += dpp0<0x118>(b);
    a += dpp0<0x142>(a);  b += dpp0<0x142>(b);
    a += dpp0<0x143>(a);  b += dpp0<0x143>(b);
    a = rdlane(a, 63);
    b = rdlane(b, 63);
}

// Support-packed Schur step k -> k+1 (R12/R15 champion, unchanged).
// P = a|F, Q = ra|B, X = x|-R;  P' = P + g*sh1(Q);  Q' = sh1(Q) + g*P;
// X' = X + mu*Q'.  Boundary: P'[k+1] <- g, X'[k+1] <- mu via cmp+cndmask.
#define STEP(KF1, KF2, LN1, LN2) do {                                   \
    float g  = -sF * isB;                                               \
    float sE = fmaf(g, sF, sB);              /* B_{k+1}[k+1] */         \
    isB = frcp_fast(sE);                                                \
    float mu = -sRt * isB;                                              \
    float rlF2 = rdlane(P[KF2], (LN2));      /* F_k[k+2]  */            \
    float rlB1 = rdlane(Q[KF1], (LN1));      /* B_k[k+1]  */            \
    float rlR2 = rdlane(X[KF2], (LN2));      /* -R_k[k+2] */            \
    sF  = fmaf(g, rlB1, rlF2);               /* F_{k+1}[k+2] */         \
    float tB2 = fmaf(g, rlF2, rlB1);         /* B_{k+1}[k+2] */         \
    sRt = fmaf(mu, tB2, rlR2);               /* -R_{k+1}[k+2] */        \
    sB  = sE;                                                           \
    float shq0 = dpp0<0x138>(Q[3]);          /* wave_shr:1 */           \
    float nQ0 = fmaf(g, P[0], shq0);                                    \
    float nQ1 = fmaf(g, P[1], Q[0]);                                    \
    float nQ2 = fmaf(g, P[2], Q[1]);                                    \
    float nQ3 = fmaf(g, P[3], Q[2]);                                    \
    float nP0 = fmaf(g, shq0, P[0]);                                    \
    float nP1 = fmaf(g, Q[0],  P[1]);                                   \
    float nP2 = fmaf(g, Q[1],  P[2]);                                   \
    float nP3 = fmaf(g, Q[2],  P[3]);                                   \
    X[0] = fmaf(mu, nQ0, X[0]);                                         \
    X[1] = fmaf(mu, nQ1, X[1]);                                         \
    X[2] = fmaf(mu, nQ2, X[2]);                                         \
    X[3] = fmaf(mu, nQ3, X[3]);                                         \
    bool bm = (lane == (LN1));               /* element k+1's lane */   \
    P[0]=nP0; P[1]=nP1; P[2]=nP2; P[3]=nP3;                             \
    Q[0]=nQ0; Q[1]=nQ1; Q[2]=nQ2; Q[3]=nQ3;                             \
    P[KF1] = bm ? g  : P[KF1];                                          \
    X[KF1] = bm ? mu : X[KF1];                                          \
} while (0)

// One block of 16 fmas for m = M..M+3 using windows U (@M-aligned) and
// V (@M+4): accumulation order per racc[c]/bacc[c] identical to R12.
#define CORR4(tq, Ut, Ur, Vt, Vr) do {                                  \
    racc[0] = fmaf(tq.x, Ut.x, racc[0]); bacc[0] = fmaf(tq.x, Ur.x, bacc[0]); \
    racc[1] = fmaf(tq.x, Ut.y, racc[1]); bacc[1] = fmaf(tq.x, Ur.y, bacc[1]); \
    racc[2] = fmaf(tq.x, Ut.z, racc[2]); bacc[2] = fmaf(tq.x, Ur.z, bacc[2]); \
    racc[3] = fmaf(tq.x, Ut.w, racc[3]); bacc[3] = fmaf(tq.x, Ur.w, bacc[3]); \
    racc[0] = fmaf(tq.y, Ut.y, racc[0]); bacc[0] = fmaf(tq.y, Ur.y, bacc[0]); \
    racc[1] = fmaf(tq.y, Ut.z, racc[1]); bacc[1] = fmaf(tq.y, Ur.z, bacc[1]); \
    racc[2] = fmaf(tq.y, Ut.w, racc[2]); bacc[2] = fmaf(tq.y, Ur.w, bacc[2]); \
    racc[3] = fmaf(tq.y, Vt.x, racc[3]); bacc[3] = fmaf(tq.y, Vr.x, bacc[3]); \
    racc[0] = fmaf(tq.z, Ut.z, racc[0]); bacc[0] = fmaf(tq.z, Ur.z, bacc[0]); \
    racc[1] = fmaf(tq.z, Ut.w, racc[1]); bacc[1] = fmaf(tq.z, Ur.w, bacc[1]); \
    racc[2] = fmaf(tq.z, Vt.x, racc[2]); bacc[2] = fmaf(tq.z, Vr.x, bacc[2]); \
    racc[3] = fmaf(tq.z, Vt.y, racc[3]); bacc[3] = fmaf(tq.z, Vr.y, bacc[3]); \
    racc[0] = fmaf(tq.w, Ut.w, racc[0]); bacc[0] = fmaf(tq.w, Ur.w, bacc[0]); \
    racc[1] = fmaf(tq.w, Vt.x, racc[1]); bacc[1] = fmaf(tq.w, Vr.x, bacc[1]); \
    racc[2] = fmaf(tq.w, Vt.y, racc[2]); bacc[2] = fmaf(tq.w, Vr.y, bacc[2]); \
    racc[3] = fmaf(tq.w, Vt.z, racc[3]); bacc[3] = fmaf(tq.w, Vr.z, bacc[3]); \
} while (0)

// One wave per batch. Schur solve of symmetric Toeplitz A v = b.
__global__ __launch_bounds__(64) void awloss_batch(
        const float* __restrict__ recon,
        const float* __restrict__ target,
        float* __restrict__ losses) {
    const int b    = blockIdx.x;
    const int lane = threadIdx.x;
    const bool l0  = (lane == 0);

    __shared__ __align__(16) float tgtp[576];   // t padded with zeros
    __shared__ __align__(16) float recp[576];   // rec at [127..382], zeros else

    const float4 tv4 = ((const float4*)(target + b * H))[lane];
    const float4 rv4 = ((const float4*)(recon  + b * H))[lane];

    #pragma unroll
    for (int c = 0; c < 9; ++c) { tgtp[c*64+lane] = 0.f; recp[c*64+lane] = 0.f; }
    __syncthreads();
    *(float4*)&tgtp[4*lane] = tv4;
    recp[127 + 4*lane + 0] = rv4.x;
    recp[127 + 4*lane + 1] = rv4.y;
    recp[127 + 4*lane + 2] = rv4.z;
    recp[127 + 4*lane + 3] = rv4.w;
    __syncthreads();

    // --- correlation r[d], b[d], lane-major d = 4*lane+c.
    //     Ping-pong windows, ALL loads hoisted to loop top: the first CORR4
    //     consumes only held registers, so 32 fmas cover the loads' latency.
    //     fma order per accumulator identical to R12 -> bitwise-same. ---
    float racc[4] = {0.f,0.f,0.f,0.f}, bacc[4] = {0.f,0.f,0.f,0.f};
    const int e0 = 4 * lane;
    float4 W0t = *(const float4*)&tgtp[e0];
    float4 W0r = *(const float4*)&recp[e0];
    float4 tqa = *(const float4*)&tgtp[0];
    for (int m0 = 0; m0 < 256; m0 += 8) {
        float4 W1t = *(const float4*)&tgtp[m0 + 4 + e0];
        float4 W1r = *(const float4*)&recp[m0 + 4 + e0];
        float4 W2t = *(const float4*)&tgtp[m0 + 8 + e0];   // max idx 511 < 576
        float4 W2r = *(const float4*)&recp[m0 + 8 + e0];
        float4 tqb = *(const float4*)&tgtp[m0 + 4];
        float4 tqn = *(const float4*)&tgtp[m0 + 8];        // next tqa (pad-safe)
        CORR4(tqa, W0t, W0r, W1t, W1r);                    // m = m0 .. m0+3
        CORR4(tqb, W1t, W1r, W2t, W2r);                    // m = m0+4 .. m0+7
        W0t = W2t; W0r = W2r; tqa = tqn;
    }

    // --- normalize; init packed state (lane-major e = 4*lane+c) ---
    float t0v = rdlane(racc[0], 0) + EPS;
    float it0 = frcp_nr(t0v);
    float P[4], Q[4], X[4];
    #pragma unroll
    for (int c = 0; c < 4; ++c) {
        float rh = racc[c] * it0;
        if (c == 0) rh = l0 ? 1.0f : rh;   // rho[0]=1; a_0[0]=1, B_0[0]=1
        P[c] = rh; Q[c] = rh;              // P = a|F = rho; Q = ra|B = rho
    }
    float bb0 = rdlane(bacc[0], 0) * it0;
    #pragma unroll
    for (int c = 0; c < 4; ++c) {
        float bvv = bacc[c] * it0;
        X[c] = fmaf(bb0, P[c], -bvv);      // -R_0 = bb0*rho - bb
    }
    if (l0) X[0] = bb0;                    // x_0[0] = bb0

    float sF  = rdlane(P[1], 0);           // F_0[1] = rho[1]
    float sB  = 1.0f, isB = 1.0f;
    float sRt = rdlane(X[1], 0);           // -R_0[1]

    // --- 255 Schur steps, x4 unrolled for literal register indices ---
    for (int t = 0; t < 63; ++t) {
        STEP(1, 2, t, t);                  // k = 4t
        STEP(2, 3, t, t);                  // k = 4t+1
        STEP(3, 0, t, t + 1);              // k = 4t+2
        STEP(0, 1, t + 1, t + 1);          // k = 4t+3
    }
    STEP(1, 2, 63, 63);                    // k = 252
    STEP(2, 3, 63, 63);                    // k = 253
    {   // k = 254: only mu and the X update matter (element 255 <- mu)
        float g  = -sF * isB;
        float sE = fmaf(g, sF, sB);
        float mu = -sRt * frcp_fast(sE);
        float shq0 = dpp0<0x138>(Q[3]);
        float nQ0 = fmaf(g, P[0], shq0);
        float nQ1 = fmaf(g, P[1], Q[0]);
        float nQ2 = fmaf(g, P[2], Q[1]);
        float nQ3 = fmaf(g, P[3], Q[2]);
        X[0] = fmaf(mu, nQ0, X[0]);
        X[1] = fmaf(mu, nQ1, X[1]);
        X[2] = fmaf(mu, nQ2, X[2]);
        X[3] = fmaf(mu, nQ3, X[3]);
        X[3] = (lane == 63) ? mu : X[3];
    }

    // --- loss: 0.5*sqrt(sum((T*v)^2)/sum(v^2)), elements e = 4*lane+c ---
    float sT = 0.f, sV = 0.f;
    const float dxg = 20.0f / 255.0f;
    #pragma unroll
    for (int c = 0; c < 4; ++c) {
        float v  = X[c];
        float u  = -10.0f + dxg * (float)(e0 + c) + 0.5f * dxg;
        float Ti = 1.0f - expf(-0.5f * u * u);   // T normalizers == 1.0f in f32
        float tw = Ti * v;
        sT += tw * tw;
        sV += v * v;
    }
    wave_red_sum2(sT, sV);
    if (l0) losses[b] = 0.5f * sqrtf(sT / sV);
}

// deterministic final reduction of 512 per-batch losses
__global__ __launch_bounds__(64) void awloss_reduce(
        const float* __restrict__ losses, float* __restrict__ out) {
    int lane = threadIdx.x;
    float s = 0.f;
    #pragma unroll
    for (int c = 0; c < 8; ++c) s += losses[c * 64 + lane];
    float d = 0.f;
    wave_red_sum2(s, d);
    if (lane == 0) out[0] = s;
}

extern "C" void kernel_launch(void* const* d_in, const int* in_sizes, int n_in,
                              void* d_out, int out_size, void* d_ws, size_t ws_size,
                              hipStream_t stream) {
    const float* recon  = (const float*)d_in[0];
    const float* target = (const float*)d_in[1];
    float* losses = (float*)d_ws;   // 512 floats
    float* out    = (float*)d_out;

    awloss_batch<<<512, 64, 0, stream>>>(recon, target, losses);
    awloss_reduce<<<1, 64, 0, stream>>>(losses, out);
}

// Round 19
// 27.254 us; speedup vs baseline: 1.4123x; 1.0456x over previous
//
#include <hip/hip_runtime.h>
#include <math.h>

#define H 256
#define EPS 1e-4f

typedef float float2v __attribute__((ext_vector_type(2)));

__device__ __forceinline__ float2v pkfma(float2v a, float2v b, float2v c) {
    return __builtin_elementwise_fma(a, b, c);   // -> v_pk_fma_f32 on gfx950
}

// ---- DPP helpers (gfx9/CDNA), bound_ctrl:0 (0-fill invalid lanes) ----
template <int CTRL>
__device__ __forceinline__ float dpp0(float x) {
    return __int_as_float(
        __builtin_amdgcn_update_dpp(0, __float_as_int(x), CTRL, 0xf, 0xf, true));
}
__device__ __forceinline__ float rdlane(float x, int l) {
    return __int_as_float(__builtin_amdgcn_readlane(__float_as_int(x), l));
}
__device__ __forceinline__ float frcp_fast(float v) { return __builtin_amdgcn_rcpf(v); }
__device__ __forceinline__ float frcp_nr(float v) {
    float r = __builtin_amdgcn_rcpf(v);
    return fmaf(r, fmaf(-v, r, 1.0f), r);
}
// full-wave sum of two values, result uniform
__device__ __forceinline__ void wave_red_sum2(float& a, float& b) {
    a += dpp0<0x111>(a);  b += dpp0<0x111>(b);
    a += dpp0<0x112>(a);  b += dpp0<0x112>(b);
    a += dpp0<0x114>(a);  b += dpp0<0x114>(b);
    a += dpp0<0x118>(a);  b += dpp0<0x118>(b);
    a += dpp0<0x142>(a);  b += dpp0<0x142>(b);
    a += dpp0<0x143>(a);  b += dpp0<0x143>(b);
    a = rdlane(a, 63);
    b = rdlane(b, 63);
}

// Support-packed Schur step, STRIDE-2 PAIRED registers (bitwise-identical
// arithmetic to R12). Element e = 4*lane + c; slot->reg map:
//   c=0 -> p0.x, c=1 -> p1.x, c=2 -> p0.y, c=3 -> p1.y
// sh1(Q): pair1' = pair0 (rename); pair0' = {dpp(Qp1.y), Qp1.x}.
// 12 fma -> 6 v_pk_fma_f32. Seam: P[k+1]<-g, X[k+1]<-mu via cmp+cndmask.
// QE1/PE2/XE2 = slot lvalues of elements k+1,k+2; PSEAM/XSEAM = slot k+1.
#define STEP(QE1, PE2, XE2, PSEAM, XSEAM, LN1, LN2) do {                \
    float g  = -sF * isB;                                               \
    float sE = fmaf(g, sF, sB);              /* B_{k+1}[k+1] */         \
    isB = frcp_fast(sE);                                                \
    float mu = -sRt * isB;                                              \
    float rlF2 = rdlane(PE2, (LN2));         /* F_k[k+2]  */            \
    float rlB1 = rdlane(QE1, (LN1));         /* B_k[k+1]  */            \
    float rlR2 = rdlane(XE2, (LN2));         /* -R_k[k+2] */            \
    sF  = fmaf(g, rlB1, rlF2);               /* F_{k+1}[k+2] */         \
    float tB2 = fmaf(g, rlF2, rlB1);         /* B_{k+1}[k+2] */         \
    sRt = fmaf(mu, tB2, rlR2);               /* -R_{k+1}[k+2] */        \
    sB  = sE;                                                           \
    float2v g2 = {g, g}, mu2 = {mu, mu};                                \
    float shq = dpp0<0x138>(Qp1.y);          /* wave_shr:1 */           \
    float2v shQ0; shQ0.x = shq; shQ0.y = Qp1.x;                         \
    float2v shQ1 = Qp0;                                                 \
    float2v nQ0 = pkfma(g2, Pp0, shQ0);                                 \
    float2v nQ1 = pkfma(g2, Pp1, shQ1);                                 \
    float2v nP0 = pkfma(g2, shQ0, Pp0);                                 \
    float2v nP1 = pkfma(g2, shQ1, Pp1);                                 \
    Xp0 = pkfma(mu2, nQ0, Xp0);                                         \
    Xp1 = pkfma(mu2, nQ1, Xp1);                                         \
    bool bm = (lane == (LN1));               /* element k+1's lane */   \
    Pp0 = nP0; Pp1 = nP1; Qp0 = nQ0; Qp1 = nQ1;                         \
    PSEAM = bm ? g  : PSEAM;                                            \
    XSEAM = bm ? mu : XSEAM;                                            \
} while (0)

// One wave per batch. Schur solve of symmetric Toeplitz A v = b.
__global__ __launch_bounds__(64) void awloss_batch(
        const float* __restrict__ recon,
        const float* __restrict__ target,
        float* __restrict__ losses) {
    const int b    = blockIdx.x;
    const int lane = threadIdx.x;
    const bool l0  = (lane == 0);

    __shared__ __align__(16) float tgtp[576];   // t padded with zeros
    __shared__ __align__(16) float recp[576];   // rec at [127..382], zeros else

    const float4 tv4 = ((const float4*)(target + b * H))[lane];
    const float4 rv4 = ((const float4*)(recon  + b * H))[lane];

    #pragma unroll
    for (int c = 0; c < 9; ++c) { tgtp[c*64+lane] = 0.f; recp[c*64+lane] = 0.f; }
    __syncthreads();
    *(float4*)&tgtp[4*lane] = tv4;
    recp[127 + 4*lane + 0] = rv4.x;
    recp[127 + 4*lane + 1] = rv4.y;
    recp[127 + 4*lane + 2] = rv4.z;
    recp[127 + 4*lane + 3] = rv4.w;
    __syncthreads();

    // --- correlation r[d], b[d]; t[m] via uniform LDS broadcast (no readlane
    //     V->S hazards); pair-aligned substeps packed (v_pk_fma_f32).
    //     Per-accumulator fma order identical to R12 -> bitwise-same sums. ---
    float2v rp0 = {0.f,0.f}, rp1 = {0.f,0.f}, bp0 = {0.f,0.f}, bp1 = {0.f,0.f};
    float4 W0t = *(const float4*)&tgtp[4*lane];
    float4 W0r = *(const float4*)&recp[4*lane];
    for (int m0 = 0; m0 < 256; m0 += 4) {
        float4 W1t = *(const float4*)&tgtp[m0 + 4 + 4*lane];
        float4 W1r = *(const float4*)&recp[m0 + 4 + 4*lane];
        float4 tq  = *(const float4*)&tgtp[m0];          // uniform broadcast
        // m = m0 (pair-aligned -> pk)
        float2v tx = {tq.x, tq.x};
        rp0 = pkfma(tx, (float2v){W0t.x, W0t.y}, rp0);
        bp0 = pkfma(tx, (float2v){W0r.x, W0r.y}, bp0);
        rp1 = pkfma(tx, (float2v){W0t.z, W0t.w}, rp1);
        bp1 = pkfma(tx, (float2v){W0r.z, W0r.w}, bp1);
        // m = m0+1 (misaligned -> scalar)
        rp0.x = fmaf(tq.y, W0t.y, rp0.x); bp0.x = fmaf(tq.y, W0r.y, bp0.x);
        rp0.y = fmaf(tq.y, W0t.z, rp0.y); bp0.y = fmaf(tq.y, W0r.z, bp0.y);
        rp1.x = fmaf(tq.y, W0t.w, rp1.x); bp1.x = fmaf(tq.y, W0r.w, bp1.x);
        rp1.y = fmaf(tq.y, W1t.x, rp1.y); bp1.y = fmaf(tq.y, W1r.x, bp1.y);
        // m = m0+2 (pair-aligned -> pk)
        float2v tz = {tq.z, tq.z};
        rp0 = pkfma(tz, (float2v){W0t.z, W0t.w}, rp0);
        bp0 = pkfma(tz, (float2v){W0r.z, W0r.w}, bp0);
        rp1 = pkfma(tz, (float2v){W1t.x, W1t.y}, rp1);
        bp1 = pkfma(tz, (float2v){W1r.x, W1r.y}, bp1);
        // m = m0+3 (misaligned -> scalar)
        rp0.x = fmaf(tq.w, W0t.w, rp0.x); bp0.x = fmaf(tq.w, W0r.w, bp0.x);
        rp0.y = fmaf(tq.w, W1t.x, rp0.y); bp0.y = fmaf(tq.w, W1r.x, bp0.y);
        rp1.x = fmaf(tq.w, W1t.y, rp1.x); bp1.x = fmaf(tq.w, W1r.y, bp1.x);
        rp1.y = fmaf(tq.w, W1t.z, rp1.y); bp1.y = fmaf(tq.w, W1r.z, bp1.y);
        W0t = W1t; W0r = W1r;
    }

    // --- normalize; init packed stride-2 state ---
    float t0v = rdlane(rp0.x, 0) + EPS;
    float it0 = frcp_nr(t0v);
    float rho0 = rp0.x * it0;  rho0 = l0 ? 1.0f : rho0;   // rho[0] = 1
    float rho1 = rp0.y * it0;
    float rho2 = rp1.x * it0;
    float rho3 = rp1.y * it0;
    float2v Pp0 = {rho0, rho2}, Pp1 = {rho1, rho3};
    float2v Qp0 = Pp0,          Qp1 = Pp1;
    float bb0 = rdlane(bp0.x, 0) * it0;
    float X0 = fmaf(bb0, rho0, -(bp0.x * it0));   // -R_0 = bb0*rho - bb
    float X1 = fmaf(bb0, rho1, -(bp0.y * it0));
    float X2 = fmaf(bb0, rho2, -(bp1.x * it0));
    float X3 = fmaf(bb0, rho3, -(bp1.y * it0));
    if (l0) X0 = bb0;                             // x_0[0] = bb0
    float2v Xp0 = {X0, X2}, Xp1 = {X1, X3};

    float sF  = rdlane(Pp1.x, 0);                 // F_0[1] = rho[1] (slot 1)
    float sB  = 1.0f, isB = 1.0f;
    float sRt = rdlane(Xp1.x, 0);                 // -R_0[1]

    // --- 255 Schur steps, x4 unrolled; slot lvalues per k mod 4 ---
    for (int t = 0; t < 63; ++t) {
        STEP(Qp1.x, Pp0.y, Xp0.y, Pp1.x, Xp1.x, t,     t    );  // k=4t   s1=1 s2=2
        STEP(Qp0.y, Pp1.y, Xp1.y, Pp0.y, Xp0.y, t,     t    );  // k=4t+1 s1=2 s2=3
        STEP(Qp1.y, Pp0.x, Xp0.x, Pp1.y, Xp1.y, t,     t + 1);  // k=4t+2 s1=3 s2=0
        STEP(Qp0.x, Pp1.x, Xp1.x, Pp0.x, Xp0.x, t + 1, t + 1);  // k=4t+3 s1=0 s2=1
    }
    STEP(Qp1.x, Pp0.y, Xp0.y, Pp1.x, Xp1.x, 63, 63);            // k=252
    STEP(Qp0.y, Pp1.y, Xp1.y, Pp0.y, Xp0.y, 63, 63);            // k=253
    {   // k = 254: only mu and the X update matter (element 255 <- mu)
        float g  = -sF * isB;
        float sE = fmaf(g, sF, sB);
        float mu = -sRt * frcp_fast(sE);
        float2v g2 = {g, g}, mu2 = {mu, mu};
        float shq = dpp0<0x138>(Qp1.y);
        float2v shQ0; shQ0.x = shq; shQ0.y = Qp1.x;
        float2v shQ1 = Qp0;
        float2v nQ0 = pkfma(g2, Pp0, shQ0);
        float2v nQ1 = pkfma(g2, Pp1, shQ1);
        Xp0 = pkfma(mu2, nQ0, Xp0);
        Xp1 = pkfma(mu2, nQ1, Xp1);
        Xp1.y = (lane == 63) ? mu : Xp1.y;        // element 255, slot 3
    }

    // --- loss: 0.5*sqrt(sum((T*v)^2)/sum(v^2)); slot->value map ---
    float v0 = Xp0.x, v1 = Xp1.x, v2 = Xp0.y, v3 = Xp1.y;
    float vs[4] = {v0, v1, v2, v3};
    float sT = 0.f, sV = 0.f;
    const float dxg = 20.0f / 255.0f;
    #pragma unroll
    for (int c = 0; c < 4; ++c) {
        float v  = vs[c];
        float u  = -10.0f + dxg * (float)(4*lane + c) + 0.5f * dxg;
        float Ti = 1.0f - expf(-0.5f * u * u);   // T normalizers == 1.0f in f32
        float tw = Ti * v;
        sT += tw * tw;
        sV += v * v;
    }
    wave_red_sum2(sT, sV);
    if (l0) losses[b] = 0.5f * sqrtf(sT / sV);
}

// deterministic final reduction of 512 per-batch losses
__global__ __launch_bounds__(64) void awloss_reduce(
        const float* __restrict__ losses, float* __restrict__ out) {
    int lane = threadIdx.x;
    float s = 0.f;
    #pragma unroll
    for (int c = 0; c < 8; ++c) s += losses[c * 64 + lane];
    float d = 0.f;
    wave_red_sum2(s, d);
    if (lane == 0) out[0] = s;
}

extern "C" void kernel_launch(void* const* d_in, const int* in_sizes, int n_in,
                              void* d_out, int out_size, void* d_ws, size_t ws_size,
                              hipStream_t stream) {
    const float* recon  = (const float*)d_in[0];
    const float* target = (const float*)d_in[1];
    float* losses = (float*)d_ws;   // 512 floats
    float* out    = (float*)d_out;

    awloss_batch<<<512, 64, 0, stream>>>(recon, target, losses);
    awloss_reduce<<<1, 64, 0, stream>>>(losses, out);
}